// Round 1
// baseline (2241.269 us; speedup 1.0000x reference)
//
#include <hip/hip_runtime.h>

#define B_ 64
#define L_ 2048
#define D_ 128
#define LP 2056   // padded rows per batch (3 left, 5 right incl. alignment)
#define PAD 3     // SAME-pad left for W=8

typedef __attribute__((ext_vector_type(8))) short short8;
typedef __attribute__((ext_vector_type(4))) float f32x4;

static __device__ __forceinline__ float bf2f(unsigned short u) {
  return __uint_as_float(((unsigned int)u) << 16);
}
static __device__ __forceinline__ unsigned short f2bf(float f) {
  unsigned int x = __float_as_uint(f);
  unsigned int r = (x + 0x7fffu + ((x >> 16) & 1u)) >> 16;  // RNE
  return (unsigned short)r;
}

// ---------------------------------------------------------------------------
// K0: gather tok -> bf16 padded [B,LP,128]; zero l1pad's pad rows; gather bias;
//     transpose weights to bf16 [n][k] layouts for MFMA B-fragments.
// ---------------------------------------------------------------------------
__global__ __launch_bounds__(256) void k_prep(
    const int* __restrict__ code, const float* __restrict__ E,
    const float* __restrict__ bias_table, const float* __restrict__ Wx,
    const float* __restrict__ c1w, const float* __restrict__ c2w,
    unsigned short* __restrict__ tokpad, unsigned short* __restrict__ l1pad,
    unsigned short* __restrict__ WxT, unsigned short* __restrict__ c1wT,
    unsigned short* __restrict__ c2wT, float* __restrict__ biasg)
{
  int id = blockIdx.x * 256 + threadIdx.x;
  const int N0 = B_ * LP * 16;            // tokpad in uint4 (8 bf16) chunks
  if (id < N0) {
    int b = id / (LP * 16); int rem = id % (LP * 16);
    int row = rem >> 4, c8 = rem & 15;
    uint4 o = {0u,0u,0u,0u};
    if (row >= PAD && row < PAD + L_) {
      int cd = code[b * L_ + (row - PAD)];
      const float4* e = (const float4*)(E + (size_t)cd * D_ + c8 * 8);
      float4 e0 = e[0], e1 = e[1];
      o.x = f2bf(e0.x) | ((unsigned int)f2bf(e0.y) << 16);
      o.y = f2bf(e0.z) | ((unsigned int)f2bf(e0.w) << 16);
      o.z = f2bf(e1.x) | ((unsigned int)f2bf(e1.y) << 16);
      o.w = f2bf(e1.z) | ((unsigned int)f2bf(e1.w) << 16);
    }
    ((uint4*)tokpad)[id] = o;
    return;
  }
  id -= N0;
  const int N1 = B_ * 8 * 8;              // l1pad pad rows (8 rows x 8 chunks)
  if (id < N1) {
    int b = id >> 6; int rem = id & 63; int ri = rem >> 3, c8 = rem & 7;
    int row = ri < 3 ? ri : (L_ + ri);    // 0,1,2, 2051..2055
    uint4 z = {0u,0u,0u,0u};
    ((uint4*)l1pad)[(b * LP + row) * 8 + c8] = z;
    return;
  }
  id -= N1;
  const int N2 = B_ * L_;
  if (id < N2) { biasg[id] = bias_table[code[id]]; return; }
  id -= N2;
  const int N3 = 192 * 128;               // WxT[c][d]
  if (id < N3) { int c = id >> 7, d = id & 127; WxT[id] = f2bf(Wx[d * 192 + c]); return; }
  id -= N3;
  const int N4 = 8 * 64 * 128;            // c1wT[w][c][d]
  if (id < N4) {
    int w = id >> 13, c = (id >> 7) & 63, d = id & 127;
    c1wT[id] = f2bf(c1w[(w * 128 + d) * 64 + c]); return;
  }
  id -= N4;
  const int N5 = 8 * 64 * 64;             // c2wT[w][c][d]
  if (id < N5) {
    int w = id >> 12, c = (id >> 6) & 63, d = id & 63;
    c2wT[id] = f2bf(c2w[(w * 64 + d) * 64 + c]);
  }
}

// ---------------------------------------------------------------------------
// K1: x_proj = tok @ Wx + b_gru[0]  -> bf16 [B,L,192]   (MFMA 16x16x32 bf16)
// ---------------------------------------------------------------------------
__global__ __launch_bounds__(256) void k_xproj(
    const unsigned short* __restrict__ tokpad, const unsigned short* __restrict__ WxT,
    const float* __restrict__ bg, unsigned short* __restrict__ xproj)
{
  __shared__ __align__(16) unsigned short At[128 * 136];
  __shared__ __align__(16) unsigned short Bt[192 * 136];
  int b = blockIdx.x >> 4;
  int l0 = (blockIdx.x & 15) << 7;
  int tid = threadIdx.x;
  for (int i = tid; i < 128 * 16; i += 256) {
    int row = i >> 4, c8 = i & 15;
    uint4 v = ((const uint4*)tokpad)[(b * LP + PAD + l0 + row) * 16 + c8];
    *((uint4*)&At[row * 136 + c8 * 8]) = v;
  }
  for (int i = tid; i < 192 * 16; i += 256) {
    int row = i >> 4, c8 = i & 15;
    uint4 v = ((const uint4*)WxT)[i];
    *((uint4*)&Bt[row * 136 + c8 * 8]) = v;
  }
  __syncthreads();
  int wave = tid >> 6, lane = tid & 63;
  int m = lane & 15, q = lane >> 4;
  f32x4 acc[2][12];
  #pragma unroll
  for (int mt = 0; mt < 2; ++mt)
    #pragma unroll
    for (int nt = 0; nt < 12; ++nt) acc[mt][nt] = (f32x4){0.f,0.f,0.f,0.f};
  #pragma unroll
  for (int ks = 0; ks < 4; ++ks) {
    int kof = ks * 32 + q * 8;
    short8 a[2], bb[12];
    #pragma unroll
    for (int mt = 0; mt < 2; ++mt)
      a[mt] = *(const short8*)&At[(wave * 32 + mt * 16 + m) * 136 + kof];
    #pragma unroll
    for (int nt = 0; nt < 12; ++nt)
      bb[nt] = *(const short8*)&Bt[(nt * 16 + m) * 136 + kof];
    #pragma unroll
    for (int mt = 0; mt < 2; ++mt)
      #pragma unroll
      for (int nt = 0; nt < 12; ++nt)
        acc[mt][nt] = __builtin_amdgcn_mfma_f32_16x16x32_bf16(a[mt], bb[nt], acc[mt][nt], 0, 0, 0);
  }
  #pragma unroll
  for (int mt = 0; mt < 2; ++mt) {
    int lrow = l0 + wave * 32 + mt * 16 + q * 4;
    #pragma unroll
    for (int nt = 0; nt < 12; ++nt) {
      int c = nt * 16 + m;                 // C col = lane&15
      float b0 = bg[c];
      #pragma unroll
      for (int r = 0; r < 4; ++r)
        xproj[(size_t)(b * L_ + lrow + r) * 192 + c] = f2bf(acc[mt][nt][r] + b0);
    }
  }
}

// ---------------------------------------------------------------------------
// K2: conv1 = relu(conv8(tok,c1w)+c1b) -> bf16 l1pad rows [3,2051)
//     GEMM: out[l] = sum_w sum_d tokpad[l+w][d] * c1wT[w][c][d]
// ---------------------------------------------------------------------------
__global__ __launch_bounds__(256) void k_conv1(
    const unsigned short* __restrict__ tokpad, const unsigned short* __restrict__ c1wT,
    const float* __restrict__ c1b, unsigned short* __restrict__ l1pad)
{
  __shared__ __align__(16) unsigned short At[135 * 136];
  __shared__ __align__(16) unsigned short Bw[64 * 136];
  int b = blockIdx.x >> 4;
  int l0 = (blockIdx.x & 15) << 7;
  int tid = threadIdx.x;
  for (int i = tid; i < 135 * 16; i += 256) {
    int row = i >> 4, c8 = i & 15;
    uint4 v = ((const uint4*)tokpad)[(b * LP + l0 + row) * 16 + c8];
    *((uint4*)&At[row * 136 + c8 * 8]) = v;
  }
  int wave = tid >> 6, lane = tid & 63;
  int m = lane & 15, q = lane >> 4;
  f32x4 acc[2][4];
  #pragma unroll
  for (int mt = 0; mt < 2; ++mt)
    #pragma unroll
    for (int nt = 0; nt < 4; ++nt) acc[mt][nt] = (f32x4){0.f,0.f,0.f,0.f};
  for (int w = 0; w < 8; ++w) {
    __syncthreads();                       // covers At (w=0) and Bw reuse
    for (int i = tid; i < 64 * 16; i += 256) {
      int row = i >> 4, c8 = i & 15;
      uint4 v = ((const uint4*)c1wT)[(w * 64 + row) * 16 + c8];
      *((uint4*)&Bw[row * 136 + c8 * 8]) = v;
    }
    __syncthreads();
    #pragma unroll
    for (int ks = 0; ks < 4; ++ks) {
      int kof = ks * 32 + q * 8;
      short8 a[2], bb[4];
      #pragma unroll
      for (int mt = 0; mt < 2; ++mt)
        a[mt] = *(const short8*)&At[(wave * 32 + mt * 16 + m + w) * 136 + kof];
      #pragma unroll
      for (int nt = 0; nt < 4; ++nt)
        bb[nt] = *(const short8*)&Bw[(nt * 16 + m) * 136 + kof];
      #pragma unroll
      for (int mt = 0; mt < 2; ++mt)
        #pragma unroll
        for (int nt = 0; nt < 4; ++nt)
          acc[mt][nt] = __builtin_amdgcn_mfma_f32_16x16x32_bf16(a[mt], bb[nt], acc[mt][nt], 0, 0, 0);
    }
  }
  #pragma unroll
  for (int mt = 0; mt < 2; ++mt) {
    int lrow = l0 + wave * 32 + mt * 16 + q * 4;
    #pragma unroll
    for (int nt = 0; nt < 4; ++nt) {
      int c = nt * 16 + m;
      float bias = c1b[c];
      #pragma unroll
      for (int r = 0; r < 4; ++r) {
        float v = fmaxf(acc[mt][nt][r] + bias, 0.f);
        l1pad[(size_t)(b * LP + PAD + lrow + r) * 64 + c] = f2bf(v);
      }
    }
  }
}

// ---------------------------------------------------------------------------
// K3: conv2 (+c2b, pre h_t multiply) -> bf16 c2out [B,L,64]
// ---------------------------------------------------------------------------
__global__ __launch_bounds__(256) void k_conv2(
    const unsigned short* __restrict__ l1pad, const unsigned short* __restrict__ c2wT,
    const float* __restrict__ c2b, unsigned short* __restrict__ c2o)
{
  __shared__ __align__(16) unsigned short At[135 * 72];
  __shared__ __align__(16) unsigned short Bw[64 * 72];
  int b = blockIdx.x >> 4;
  int l0 = (blockIdx.x & 15) << 7;
  int tid = threadIdx.x;
  for (int i = tid; i < 135 * 8; i += 256) {
    int row = i >> 3, c8 = i & 7;
    uint4 v = ((const uint4*)l1pad)[(b * LP + l0 + row) * 8 + c8];
    *((uint4*)&At[row * 72 + c8 * 8]) = v;
  }
  int wave = tid >> 6, lane = tid & 63;
  int m = lane & 15, q = lane >> 4;
  f32x4 acc[2][4];
  #pragma unroll
  for (int mt = 0; mt < 2; ++mt)
    #pragma unroll
    for (int nt = 0; nt < 4; ++nt) acc[mt][nt] = (f32x4){0.f,0.f,0.f,0.f};
  for (int w = 0; w < 8; ++w) {
    __syncthreads();
    for (int i = tid; i < 64 * 8; i += 256) {
      int row = i >> 3, c8 = i & 7;
      uint4 v = ((const uint4*)c2wT)[(w * 64 + row) * 8 + c8];
      *((uint4*)&Bw[row * 72 + c8 * 8]) = v;
    }
    __syncthreads();
    #pragma unroll
    for (int ks = 0; ks < 2; ++ks) {
      int kof = ks * 32 + q * 8;
      short8 a[2], bb[4];
      #pragma unroll
      for (int mt = 0; mt < 2; ++mt)
        a[mt] = *(const short8*)&At[(wave * 32 + mt * 16 + m + w) * 72 + kof];
      #pragma unroll
      for (int nt = 0; nt < 4; ++nt)
        bb[nt] = *(const short8*)&Bw[(nt * 16 + m) * 72 + kof];
      #pragma unroll
      for (int mt = 0; mt < 2; ++mt)
        #pragma unroll
        for (int nt = 0; nt < 4; ++nt)
          acc[mt][nt] = __builtin_amdgcn_mfma_f32_16x16x32_bf16(a[mt], bb[nt], acc[mt][nt], 0, 0, 0);
    }
  }
  #pragma unroll
  for (int mt = 0; mt < 2; ++mt) {
    int lrow = l0 + wave * 32 + mt * 16 + q * 4;
    #pragma unroll
    for (int nt = 0; nt < 4; ++nt) {
      int c = nt * 16 + m;
      float bias = c2b[c];
      #pragma unroll
      for (int r = 0; r < 4; ++r)
        c2o[(size_t)(b * L_ + lrow + r) * 64 + c] = f2bf(acc[mt][nt][r] + bias);
    }
  }
}

// ---------------------------------------------------------------------------
// K4: GRU scan, 1 wave per batch element. Wh columns in registers (192 VGPRs),
//     h broadcast via LDS (16x ds_read_b128), x_proj prefetched 1 step ahead.
// ---------------------------------------------------------------------------
__global__ __launch_bounds__(64, 1) void k_scan(
    const unsigned short* __restrict__ xproj, const float* __restrict__ Wh,
    const float* __restrict__ bg, float* __restrict__ h_t)
{
  int b = blockIdx.x, j = threadIdx.x;
  float wz[64], wr[64], wh[64];
  #pragma unroll
  for (int k = 0; k < 64; ++k) {
    wz[k] = Wh[k * 192 + j];
    wr[k] = Wh[k * 192 + 64 + j];
    wh[k] = Wh[k * 192 + 128 + j];
  }
  float bz = bg[192 + j], br = bg[256 + j], bh = bg[320 + j];
  __shared__ __align__(16) float h_lds[64];
  h_lds[j] = 0.f;
  float hj = 0.f;
  const unsigned short* xp = xproj + (size_t)b * L_ * 192;
  unsigned short pz = xp[j], pr = xp[64 + j], ph = xp[128 + j];
  __syncthreads();
  for (int t = 0; t < L_; ++t) {
    int tn = (t + 1 < L_) ? t + 1 : (L_ - 1);
    const unsigned short* xq = xp + (size_t)tn * 192;
    unsigned short nz = xq[j], nr = xq[64 + j], nh = xq[128 + j];
    float az = bz, ar = br, ah = bh;
    #pragma unroll
    for (int k4 = 0; k4 < 16; ++k4) {
      float4 h4 = ((const float4*)h_lds)[k4];
      az += h4.x * wz[4*k4] + h4.y * wz[4*k4+1] + h4.z * wz[4*k4+2] + h4.w * wz[4*k4+3];
      ar += h4.x * wr[4*k4] + h4.y * wr[4*k4+1] + h4.z * wr[4*k4+2] + h4.w * wr[4*k4+3];
      ah += h4.x * wh[4*k4] + h4.y * wh[4*k4+1] + h4.z * wh[4*k4+2] + h4.w * wh[4*k4+3];
    }
    float xz = bf2f(pz), xr = bf2f(pr), xh = bf2f(ph);
    float z = 1.f / (1.f + __expf(-(xz + az)));
    float r = 1.f / (1.f + __expf(-(xr + ar)));
    float e2 = __expf(-2.f * (xh + r * ah));
    float hhv = (1.f - e2) / (1.f + e2);         // tanh
    hj = z * hj + (1.f - z) * hhv;
    __syncthreads();                              // all reads of h_lds done
    h_lds[j] = hj;
    __syncthreads();                              // h_lds visible
    pz = nz; pr = nr; ph = nh;
  }
  h_t[b * 64 + j] = hj;
}

// ---------------------------------------------------------------------------
// K5: per-batch tail: L2=c2o*h_t -> l2norm -> conv3 -> softmax alpha ->
//     n_hat = sum alpha*tok -> logits = tok.n_hat + bias -> softmax -> out
// ---------------------------------------------------------------------------
__global__ __launch_bounds__(256) void k_final(
    const unsigned short* __restrict__ tokpad, const unsigned short* __restrict__ c2o,
    const float* __restrict__ h_t, const float* __restrict__ c3w,
    const float* __restrict__ c3b, const float* __restrict__ biasg,
    float* __restrict__ out)
{
  __shared__ float Lf[71 * 65];
  __shared__ float a_lds[2048];
  __shared__ float l_lds[2048];
  __shared__ float red[256];
  __shared__ float nred[512];
  __shared__ float nhat[128];
  __shared__ float ht[64];
  __shared__ float c3[512];
  int b = blockIdx.x, tid = threadIdx.x, lane = tid & 63, wave = tid >> 6;
  if (tid < 64) ht[tid] = h_t[b * 64 + tid];
  for (int i = tid; i < 512; i += 256) c3[i] = c3w[i];
  float c3bias = c3b[0];
  __syncthreads();
  // ---- pass 1: a_logits via normalized features + conv3 (tiles of 64 l) ----
  for (int tile = 0; tile < 32; ++tile) {
    int lt = tile << 6;
    for (int i0 = wave; i0 < 71; i0 += 4) {
      int l = lt - 3 + i0;
      float v = 0.f;
      if (l >= 0 && l < L_) v = bf2f(c2o[((size_t)b * L_ + l) * 64 + lane]) * ht[lane];
      float ss = v * v;
      #pragma unroll
      for (int msk = 1; msk < 64; msk <<= 1) ss += __shfl_xor(ss, msk);
      Lf[i0 * 65 + lane] = v * rsqrtf(ss + 1e-12f);
    }
    __syncthreads();
    {
      int u = lane, part = wave;
      float p = 0.f;
      #pragma unroll
      for (int w = 0; w < 8; ++w)
        #pragma unroll
        for (int cc = 0; cc < 16; ++cc) {
          int c = part * 16 + cc;
          p += Lf[(u + w) * 65 + c] * c3[w * 64 + c];
        }
      red[tid] = p;
    }
    __syncthreads();
    if (tid < 64) a_lds[lt + tid] = red[tid] + red[64 + tid] + red[128 + tid] + red[192 + tid] + c3bias;
    __syncthreads();
  }
  // ---- pass 2: softmax alpha over 2048 ----
  {
    float mx = -1e30f;
    for (int i = tid; i < 2048; i += 256) mx = fmaxf(mx, a_lds[i]);
    #pragma unroll
    for (int msk = 1; msk < 64; msk <<= 1) mx = fmaxf(mx, __shfl_xor(mx, msk));
    if (lane == 0) red[wave] = mx;
    __syncthreads();
    mx = fmaxf(fmaxf(red[0], red[1]), fmaxf(red[2], red[3]));
    float sm = 0.f;
    for (int i = tid; i < 2048; i += 256) sm += __expf(a_lds[i] - mx);
    #pragma unroll
    for (int msk = 1; msk < 64; msk <<= 1) sm += __shfl_xor(sm, msk);
    __syncthreads();
    if (lane == 0) red[wave] = sm;
    __syncthreads();
    sm = red[0] + red[1] + red[2] + red[3];
    float inv = 1.f / sm;
    for (int i = tid; i < 2048; i += 256) a_lds[i] = __expf(a_lds[i] - mx) * inv;
    __syncthreads();
  }
  // ---- pass 3: n_hat[128] = sum_l alpha_l * tok[l][:] ----
  {
    int d2 = tid & 63, g = tid >> 6;
    float ax = 0.f, ay = 0.f;
    for (int l = g; l < L_; l += 4) {
      unsigned int uu = *(const unsigned int*)&tokpad[((size_t)b * LP + PAD + l) * 128 + d2 * 2];
      float al = a_lds[l];
      ax += al * bf2f((unsigned short)(uu & 0xffffu));
      ay += al * bf2f((unsigned short)(uu >> 16));
    }
    nred[g * 128 + d2 * 2] = ax;
    nred[g * 128 + d2 * 2 + 1] = ay;
    __syncthreads();
    if (tid < 128) nhat[tid] = nred[tid] + nred[128 + tid] + nred[256 + tid] + nred[384 + tid];
    __syncthreads();
  }
  // ---- pass 4: logits = tok . n_hat + bias ----
  for (int li = 0; li < 8; ++li) {
    int l = li * 256 + tid;
    const uint4* rowp = (const uint4*)&tokpad[((size_t)b * LP + PAD + l) * 128];
    float s = 0.f;
    #pragma unroll
    for (int jj = 0; jj < 16; ++jj) {
      uint4 uu = rowp[jj];
      s += bf2f((unsigned short)(uu.x & 0xffffu)) * nhat[jj*8+0]
         + bf2f((unsigned short)(uu.x >> 16))     * nhat[jj*8+1]
         + bf2f((unsigned short)(uu.y & 0xffffu)) * nhat[jj*8+2]
         + bf2f((unsigned short)(uu.y >> 16))     * nhat[jj*8+3]
         + bf2f((unsigned short)(uu.z & 0xffffu)) * nhat[jj*8+4]
         + bf2f((unsigned short)(uu.z >> 16))     * nhat[jj*8+5]
         + bf2f((unsigned short)(uu.w & 0xffffu)) * nhat[jj*8+6]
         + bf2f((unsigned short)(uu.w >> 16))     * nhat[jj*8+7];
    }
    l_lds[l] = s + biasg[b * L_ + l];
  }
  __syncthreads();
  // ---- pass 5: final softmax -> out ----
  {
    float mx = -1e30f;
    for (int i = tid; i < 2048; i += 256) mx = fmaxf(mx, l_lds[i]);
    #pragma unroll
    for (int msk = 1; msk < 64; msk <<= 1) mx = fmaxf(mx, __shfl_xor(mx, msk));
    __syncthreads();
    if (lane == 0) red[wave] = mx;
    __syncthreads();
    mx = fmaxf(fmaxf(red[0], red[1]), fmaxf(red[2], red[3]));
    float sm = 0.f;
    for (int i = tid; i < 2048; i += 256) sm += __expf(l_lds[i] - mx);
    #pragma unroll
    for (int msk = 1; msk < 64; msk <<= 1) sm += __shfl_xor(sm, msk);
    __syncthreads();
    if (lane == 0) red[wave] = sm;
    __syncthreads();
    sm = red[0] + red[1] + red[2] + red[3];
    float inv = 1.f / sm;
    for (int i = tid; i < 2048; i += 256) out[b * L_ + i] = __expf(l_lds[i] - mx) * inv;
  }
}

// ---------------------------------------------------------------------------
extern "C" void kernel_launch(void* const* d_in, const int* in_sizes, int n_in,
                              void* d_out, int out_size, void* d_ws, size_t ws_size,
                              hipStream_t stream) {
  const int*   code = (const int*)d_in[0];
  const float* E    = (const float*)d_in[1];
  const float* bt   = (const float*)d_in[2];
  const float* Wx   = (const float*)d_in[3];
  const float* Wh   = (const float*)d_in[4];
  const float* bg   = (const float*)d_in[5];
  const float* c1w  = (const float*)d_in[6];
  const float* c1b  = (const float*)d_in[7];
  const float* c2w  = (const float*)d_in[8];
  const float* c2b  = (const float*)d_in[9];
  const float* c3w  = (const float*)d_in[10];
  const float* c3b  = (const float*)d_in[11];
  char* ws = (char*)d_ws;
  unsigned short* tokpad = (unsigned short*)(ws);               // 33,685,504 B
  unsigned short* l1pad  = (unsigned short*)(ws + 33685504);    // 16,842,752 B
  unsigned short* xproj  = (unsigned short*)(ws + 50528256);    // 50,331,648 B
  unsigned short* c2o    = (unsigned short*)(ws + 100859904);   // 16,777,216 B
  unsigned short* WxT    = (unsigned short*)(ws + 117637120);   //     49,152 B
  unsigned short* c1wT   = (unsigned short*)(ws + 117686272);   //    131,072 B
  unsigned short* c2wT   = (unsigned short*)(ws + 117817344);   //     65,536 B
  float*          htp    = (float*)(ws + 117882880);            //     16,384 B
  float*          biasg  = (float*)(ws + 117899264);            //    524,288 B
  // total ws use: 118,423,552 B

  k_prep <<<9232, 256, 0, stream>>>(code, E, bt, Wx, c1w, c2w, tokpad, l1pad, WxT, c1wT, c2wT, biasg);
  k_xproj<<<1024, 256, 0, stream>>>(tokpad, WxT, bg, xproj);
  k_conv1<<<1024, 256, 0, stream>>>(tokpad, c1wT, c1b, l1pad);
  k_conv2<<<1024, 256, 0, stream>>>(l1pad, c2wT, c2b, c2o);
  k_scan <<<64, 64, 0, stream>>>(xproj, Wh, bg, htp);
  k_final<<<64, 256, 0, stream>>>(tokpad, c2o, htp, c3w, c3b, biasg, (float*)d_out);
}

// Round 2
// 1767.587 us; speedup vs baseline: 1.2680x; 1.2680x over previous
//
#include <hip/hip_runtime.h>

#define B_ 64
#define L_ 2048
#define D_ 128
#define LP 2056   // padded rows per batch (3 left, 5 right incl. alignment)
#define PAD 3     // SAME-pad left for W=8

typedef __attribute__((ext_vector_type(8))) short short8;
typedef __attribute__((ext_vector_type(4))) float f32x4;

static __device__ __forceinline__ float bf2f(unsigned short u) {
  return __uint_as_float(((unsigned int)u) << 16);
}
static __device__ __forceinline__ unsigned short f2bf(float f) {
  unsigned int x = __float_as_uint(f);
  unsigned int r = (x + 0x7fffu + ((x >> 16) & 1u)) >> 16;  // RNE
  return (unsigned short)r;
}

// ---------------------------------------------------------------------------
// K0: gather tok -> bf16 padded [B,LP,128]; zero l1pad's pad rows; gather bias;
//     transpose weights to bf16 [n][k] layouts for MFMA B-fragments.
// ---------------------------------------------------------------------------
__global__ __launch_bounds__(256) void k_prep(
    const int* __restrict__ code, const float* __restrict__ E,
    const float* __restrict__ bias_table, const float* __restrict__ Wx,
    const float* __restrict__ c1w, const float* __restrict__ c2w,
    unsigned short* __restrict__ tokpad, unsigned short* __restrict__ l1pad,
    unsigned short* __restrict__ WxT, unsigned short* __restrict__ c1wT,
    unsigned short* __restrict__ c2wT, float* __restrict__ biasg)
{
  int id = blockIdx.x * 256 + threadIdx.x;
  const int N0 = B_ * LP * 16;            // tokpad in uint4 (8 bf16) chunks
  if (id < N0) {
    int b = id / (LP * 16); int rem = id % (LP * 16);
    int row = rem >> 4, c8 = rem & 15;
    uint4 o = {0u,0u,0u,0u};
    if (row >= PAD && row < PAD + L_) {
      int cd = code[b * L_ + (row - PAD)];
      const float4* e = (const float4*)(E + (size_t)cd * D_ + c8 * 8);
      float4 e0 = e[0], e1 = e[1];
      o.x = f2bf(e0.x) | ((unsigned int)f2bf(e0.y) << 16);
      o.y = f2bf(e0.z) | ((unsigned int)f2bf(e0.w) << 16);
      o.z = f2bf(e1.x) | ((unsigned int)f2bf(e1.y) << 16);
      o.w = f2bf(e1.z) | ((unsigned int)f2bf(e1.w) << 16);
    }
    ((uint4*)tokpad)[id] = o;
    return;
  }
  id -= N0;
  const int N1 = B_ * 8 * 8;              // l1pad pad rows (8 rows x 8 chunks)
  if (id < N1) {
    int b = id >> 6; int rem = id & 63; int ri = rem >> 3, c8 = rem & 7;
    int row = ri < 3 ? ri : (L_ + ri);    // 0,1,2, 2051..2055
    uint4 z = {0u,0u,0u,0u};
    ((uint4*)l1pad)[(b * LP + row) * 8 + c8] = z;
    return;
  }
  id -= N1;
  const int N2 = B_ * L_;
  if (id < N2) { biasg[id] = bias_table[code[id]]; return; }
  id -= N2;
  const int N3 = 192 * 128;               // WxT[c][d]
  if (id < N3) { int c = id >> 7, d = id & 127; WxT[id] = f2bf(Wx[d * 192 + c]); return; }
  id -= N3;
  const int N4 = 8 * 64 * 128;            // c1wT[w][c][d]
  if (id < N4) {
    int w = id >> 13, c = (id >> 7) & 63, d = id & 127;
    c1wT[id] = f2bf(c1w[(w * 128 + d) * 64 + c]); return;
  }
  id -= N4;
  const int N5 = 8 * 64 * 64;             // c2wT[w][c][d]
  if (id < N5) {
    int w = id >> 12, c = (id >> 6) & 63, d = id & 63;
    c2wT[id] = f2bf(c2w[(w * 64 + d) * 64 + c]);
  }
}

// ---------------------------------------------------------------------------
// K1: x_proj = tok @ Wx + b_gru[0]  -> bf16 [B,L,192]   (MFMA 16x16x32 bf16)
// ---------------------------------------------------------------------------
__global__ __launch_bounds__(256) void k_xproj(
    const unsigned short* __restrict__ tokpad, const unsigned short* __restrict__ WxT,
    const float* __restrict__ bg, unsigned short* __restrict__ xproj)
{
  __shared__ __align__(16) unsigned short At[128 * 136];
  __shared__ __align__(16) unsigned short Bt[192 * 136];
  int b = blockIdx.x >> 4;
  int l0 = (blockIdx.x & 15) << 7;
  int tid = threadIdx.x;
  for (int i = tid; i < 128 * 16; i += 256) {
    int row = i >> 4, c8 = i & 15;
    uint4 v = ((const uint4*)tokpad)[(b * LP + PAD + l0 + row) * 16 + c8];
    *((uint4*)&At[row * 136 + c8 * 8]) = v;
  }
  for (int i = tid; i < 192 * 16; i += 256) {
    int row = i >> 4, c8 = i & 15;
    uint4 v = ((const uint4*)WxT)[i];
    *((uint4*)&Bt[row * 136 + c8 * 8]) = v;
  }
  __syncthreads();
  int wave = tid >> 6, lane = tid & 63;
  int m = lane & 15, q = lane >> 4;
  f32x4 acc[2][12];
  #pragma unroll
  for (int mt = 0; mt < 2; ++mt)
    #pragma unroll
    for (int nt = 0; nt < 12; ++nt) acc[mt][nt] = (f32x4){0.f,0.f,0.f,0.f};
  #pragma unroll
  for (int ks = 0; ks < 4; ++ks) {
    int kof = ks * 32 + q * 8;
    short8 a[2], bb[12];
    #pragma unroll
    for (int mt = 0; mt < 2; ++mt)
      a[mt] = *(const short8*)&At[(wave * 32 + mt * 16 + m) * 136 + kof];
    #pragma unroll
    for (int nt = 0; nt < 12; ++nt)
      bb[nt] = *(const short8*)&Bt[(nt * 16 + m) * 136 + kof];
    #pragma unroll
    for (int mt = 0; mt < 2; ++mt)
      #pragma unroll
      for (int nt = 0; nt < 12; ++nt)
        acc[mt][nt] = __builtin_amdgcn_mfma_f32_16x16x32_bf16(a[mt], bb[nt], acc[mt][nt], 0, 0, 0);
  }
  #pragma unroll
  for (int mt = 0; mt < 2; ++mt) {
    int lrow = l0 + wave * 32 + mt * 16 + q * 4;
    #pragma unroll
    for (int nt = 0; nt < 12; ++nt) {
      int c = nt * 16 + m;                 // C col = lane&15
      float b0 = bg[c];
      #pragma unroll
      for (int r = 0; r < 4; ++r)
        xproj[(size_t)(b * L_ + lrow + r) * 192 + c] = f2bf(acc[mt][nt][r] + b0);
    }
  }
}

// ---------------------------------------------------------------------------
// K2: conv1 = relu(conv8(tok,c1w)+c1b) -> bf16 l1pad rows [3,2051)
// ---------------------------------------------------------------------------
__global__ __launch_bounds__(256) void k_conv1(
    const unsigned short* __restrict__ tokpad, const unsigned short* __restrict__ c1wT,
    const float* __restrict__ c1b, unsigned short* __restrict__ l1pad)
{
  __shared__ __align__(16) unsigned short At[135 * 136];
  __shared__ __align__(16) unsigned short Bw[64 * 136];
  int b = blockIdx.x >> 4;
  int l0 = (blockIdx.x & 15) << 7;
  int tid = threadIdx.x;
  for (int i = tid; i < 135 * 16; i += 256) {
    int row = i >> 4, c8 = i & 15;
    uint4 v = ((const uint4*)tokpad)[(b * LP + l0 + row) * 16 + c8];
    *((uint4*)&At[row * 136 + c8 * 8]) = v;
  }
  int wave = tid >> 6, lane = tid & 63;
  int m = lane & 15, q = lane >> 4;
  f32x4 acc[2][4];
  #pragma unroll
  for (int mt = 0; mt < 2; ++mt)
    #pragma unroll
    for (int nt = 0; nt < 4; ++nt) acc[mt][nt] = (f32x4){0.f,0.f,0.f,0.f};
  for (int w = 0; w < 8; ++w) {
    __syncthreads();                       // covers At (w=0) and Bw reuse
    for (int i = tid; i < 64 * 16; i += 256) {
      int row = i >> 4, c8 = i & 15;
      uint4 v = ((const uint4*)c1wT)[(w * 64 + row) * 16 + c8];
      *((uint4*)&Bw[row * 136 + c8 * 8]) = v;
    }
    __syncthreads();
    #pragma unroll
    for (int ks = 0; ks < 4; ++ks) {
      int kof = ks * 32 + q * 8;
      short8 a[2], bb[4];
      #pragma unroll
      for (int mt = 0; mt < 2; ++mt)
        a[mt] = *(const short8*)&At[(wave * 32 + mt * 16 + m + w) * 136 + kof];
      #pragma unroll
      for (int nt = 0; nt < 4; ++nt)
        bb[nt] = *(const short8*)&Bw[(nt * 16 + m) * 136 + kof];
      #pragma unroll
      for (int mt = 0; mt < 2; ++mt)
        #pragma unroll
        for (int nt = 0; nt < 4; ++nt)
          acc[mt][nt] = __builtin_amdgcn_mfma_f32_16x16x32_bf16(a[mt], bb[nt], acc[mt][nt], 0, 0, 0);
    }
  }
  #pragma unroll
  for (int mt = 0; mt < 2; ++mt) {
    int lrow = l0 + wave * 32 + mt * 16 + q * 4;
    #pragma unroll
    for (int nt = 0; nt < 4; ++nt) {
      int c = nt * 16 + m;
      float bias = c1b[c];
      #pragma unroll
      for (int r = 0; r < 4; ++r) {
        float v = fmaxf(acc[mt][nt][r] + bias, 0.f);
        l1pad[(size_t)(b * LP + PAD + lrow + r) * 64 + c] = f2bf(v);
      }
    }
  }
}

// ---------------------------------------------------------------------------
// K3: conv2 (+c2b, pre h_t multiply) -> bf16 c2out [B,L,64]
// ---------------------------------------------------------------------------
__global__ __launch_bounds__(256) void k_conv2(
    const unsigned short* __restrict__ l1pad, const unsigned short* __restrict__ c2wT,
    const float* __restrict__ c2b, unsigned short* __restrict__ c2o)
{
  __shared__ __align__(16) unsigned short At[135 * 72];
  __shared__ __align__(16) unsigned short Bw[64 * 72];
  int b = blockIdx.x >> 4;
  int l0 = (blockIdx.x & 15) << 7;
  int tid = threadIdx.x;
  for (int i = tid; i < 135 * 8; i += 256) {
    int row = i >> 3, c8 = i & 7;
    uint4 v = ((const uint4*)l1pad)[(b * LP + l0 + row) * 8 + c8];
    *((uint4*)&At[row * 72 + c8 * 8]) = v;
  }
  int wave = tid >> 6, lane = tid & 63;
  int m = lane & 15, q = lane >> 4;
  f32x4 acc[2][4];
  #pragma unroll
  for (int mt = 0; mt < 2; ++mt)
    #pragma unroll
    for (int nt = 0; nt < 4; ++nt) acc[mt][nt] = (f32x4){0.f,0.f,0.f,0.f};
  for (int w = 0; w < 8; ++w) {
    __syncthreads();
    for (int i = tid; i < 64 * 8; i += 256) {
      int row = i >> 3, c8 = i & 7;
      uint4 v = ((const uint4*)c2wT)[(w * 64 + row) * 8 + c8];
      *((uint4*)&Bw[row * 72 + c8 * 8]) = v;
    }
    __syncthreads();
    #pragma unroll
    for (int ks = 0; ks < 2; ++ks) {
      int kof = ks * 32 + q * 8;
      short8 a[2], bb[4];
      #pragma unroll
      for (int mt = 0; mt < 2; ++mt)
        a[mt] = *(const short8*)&At[(wave * 32 + mt * 16 + m + w) * 72 + kof];
      #pragma unroll
      for (int nt = 0; nt < 4; ++nt)
        bb[nt] = *(const short8*)&Bw[(nt * 16 + m) * 72 + kof];
      #pragma unroll
      for (int mt = 0; mt < 2; ++mt)
        #pragma unroll
        for (int nt = 0; nt < 4; ++nt)
          acc[mt][nt] = __builtin_amdgcn_mfma_f32_16x16x32_bf16(a[mt], bb[nt], acc[mt][nt], 0, 0, 0);
    }
  }
  #pragma unroll
  for (int mt = 0; mt < 2; ++mt) {
    int lrow = l0 + wave * 32 + mt * 16 + q * 4;
    #pragma unroll
    for (int nt = 0; nt < 4; ++nt) {
      int c = nt * 16 + m;
      float bias = c2b[c];
      #pragma unroll
      for (int r = 0; r < 4; ++r)
        c2o[(size_t)(b * L_ + lrow + r) * 64 + c] = f2bf(acc[mt][nt][r] + bias);
    }
  }
}

// ---------------------------------------------------------------------------
// K4 v2: GRU scan. 3 waves per batch (one per gate). Lane o = wave*64+j owns
// output column o: 64 Wh weights in VGPRs (no spill). Waves 0/1 write
// x+preact for z/r to LDS; wave 2 keeps hh_ preact in register, combines,
// writes h. 2 barriers/step. x_proj prefetched 2 steps ahead.
// ---------------------------------------------------------------------------
__global__ __launch_bounds__(192, 1) void k_scan(
    const unsigned short* __restrict__ xproj, const float* __restrict__ Wh,
    const float* __restrict__ bg, float* __restrict__ h_t)
{
  int b = blockIdx.x;
  int tid = threadIdx.x;
  int wave = tid >> 6, j = tid & 63;
  int o = wave * 64 + j;                  // output column 0..191

  float w[64];
  #pragma unroll
  for (int k = 0; k < 64; ++k) w[k] = Wh[k * 192 + o];
  float bias = bg[192 + o];               // b_gru[1][o]

  __shared__ __align__(16) float h_lds[64];
  __shared__ float s_z[64];
  __shared__ float s_r[64];
  if (wave == 2) h_lds[j] = 0.f;
  float h_old = 0.f;                      // wave2's private copy of h[j]

  const unsigned short* xp = xproj + (size_t)b * L_ * 192 + o;
  unsigned short x0 = xp[0];
  unsigned short x1 = xp[192];

  for (int t = 0; t < L_; ++t) {
    __syncthreads();                      // barrier A: h_lds ready, s_* free
    int tn = (t + 2 < L_) ? t + 2 : (L_ - 1);
    unsigned short x2 = xp[(size_t)tn * 192];

    float a0 = bias, a1 = 0.f, a2 = 0.f, a3 = 0.f;
    #pragma unroll
    for (int k4 = 0; k4 < 16; ++k4) {
      float4 h4 = ((const float4*)h_lds)[k4];
      a0 += h4.x * w[4 * k4 + 0];
      a1 += h4.y * w[4 * k4 + 1];
      a2 += h4.z * w[4 * k4 + 2];
      a3 += h4.w * w[4 * k4 + 3];
    }
    float s = (a0 + a1) + (a2 + a3);      // recurrent preact for column o
    float xv = bf2f(x0);

    if (wave == 0) s_z[j] = xv + s;
    else if (wave == 1) s_r[j] = xv + s;
    __syncthreads();                      // barrier B: s_z/s_r visible
    if (wave == 2) {
      float vz = s_z[j], vr = s_r[j];
      float z = 1.f / (1.f + __expf(-vz));
      float r = 1.f / (1.f + __expf(-vr));
      float e2 = __expf(-2.f * (xv + r * s));
      float hh = (1.f - e2) / (1.f + e2); // tanh
      h_old = z * h_old + (1.f - z) * hh;
      h_lds[j] = h_old;
    }
    x0 = x1; x1 = x2;
  }
  if (wave == 2) h_t[b * 64 + j] = h_old;
}

// ---------------------------------------------------------------------------
// K5: per-batch tail: L2=c2o*h_t -> l2norm -> conv3 -> softmax alpha ->
//     n_hat = sum alpha*tok -> logits = tok.n_hat + bias -> softmax -> out
// ---------------------------------------------------------------------------
__global__ __launch_bounds__(256) void k_final(
    const unsigned short* __restrict__ tokpad, const unsigned short* __restrict__ c2o,
    const float* __restrict__ h_t, const float* __restrict__ c3w,
    const float* __restrict__ c3b, const float* __restrict__ biasg,
    float* __restrict__ out)
{
  __shared__ float Lf[71 * 65];
  __shared__ float a_lds[2048];
  __shared__ float l_lds[2048];
  __shared__ float red[256];
  __shared__ float nred[512];
  __shared__ float nhat[128];
  __shared__ float ht[64];
  __shared__ float c3[512];
  int b = blockIdx.x, tid = threadIdx.x, lane = tid & 63, wave = tid >> 6;
  if (tid < 64) ht[tid] = h_t[b * 64 + tid];
  for (int i = tid; i < 512; i += 256) c3[i] = c3w[i];
  float c3bias = c3b[0];
  __syncthreads();
  // ---- pass 1: a_logits via normalized features + conv3 (tiles of 64 l) ----
  for (int tile = 0; tile < 32; ++tile) {
    int lt = tile << 6;
    for (int i0 = wave; i0 < 71; i0 += 4) {
      int l = lt - 3 + i0;
      float v = 0.f;
      if (l >= 0 && l < L_) v = bf2f(c2o[((size_t)b * L_ + l) * 64 + lane]) * ht[lane];
      float ss = v * v;
      #pragma unroll
      for (int msk = 1; msk < 64; msk <<= 1) ss += __shfl_xor(ss, msk);
      Lf[i0 * 65 + lane] = v * rsqrtf(ss + 1e-12f);
    }
    __syncthreads();
    {
      int u = lane, part = wave;
      float p = 0.f;
      #pragma unroll
      for (int w = 0; w < 8; ++w)
        #pragma unroll
        for (int cc = 0; cc < 16; ++cc) {
          int c = part * 16 + cc;
          p += Lf[(u + w) * 65 + c] * c3[w * 64 + c];
        }
      red[tid] = p;
    }
    __syncthreads();
    if (tid < 64) a_lds[lt + tid] = red[tid] + red[64 + tid] + red[128 + tid] + red[192 + tid] + c3bias;
    __syncthreads();
  }
  // ---- pass 2: softmax alpha over 2048 ----
  {
    float mx = -1e30f;
    for (int i = tid; i < 2048; i += 256) mx = fmaxf(mx, a_lds[i]);
    #pragma unroll
    for (int msk = 1; msk < 64; msk <<= 1) mx = fmaxf(mx, __shfl_xor(mx, msk));
    if (lane == 0) red[wave] = mx;
    __syncthreads();
    mx = fmaxf(fmaxf(red[0], red[1]), fmaxf(red[2], red[3]));
    float sm = 0.f;
    for (int i = tid; i < 2048; i += 256) sm += __expf(a_lds[i] - mx);
    #pragma unroll
    for (int msk = 1; msk < 64; msk <<= 1) sm += __shfl_xor(sm, msk);
    __syncthreads();
    if (lane == 0) red[wave] = sm;
    __syncthreads();
    sm = red[0] + red[1] + red[2] + red[3];
    float inv = 1.f / sm;
    for (int i = tid; i < 2048; i += 256) a_lds[i] = __expf(a_lds[i] - mx) * inv;
    __syncthreads();
  }
  // ---- pass 3: n_hat[128] = sum_l alpha_l * tok[l][:] ----
  {
    int d2 = tid & 63, g = tid >> 6;
    float ax = 0.f, ay = 0.f;
    for (int l = g; l < L_; l += 4) {
      unsigned int uu = *(const unsigned int*)&tokpad[((size_t)b * LP + PAD + l) * 128 + d2 * 2];
      float al = a_lds[l];
      ax += al * bf2f((unsigned short)(uu & 0xffffu));
      ay += al * bf2f((unsigned short)(uu >> 16));
    }
    nred[g * 128 + d2 * 2] = ax;
    nred[g * 128 + d2 * 2 + 1] = ay;
    __syncthreads();
    if (tid < 128) nhat[tid] = nred[tid] + nred[128 + tid] + nred[256 + tid] + nred[384 + tid];
    __syncthreads();
  }
  // ---- pass 4: logits = tok . n_hat + bias ----
  for (int li = 0; li < 8; ++li) {
    int l = li * 256 + tid;
    const uint4* rowp = (const uint4*)&tokpad[((size_t)b * LP + PAD + l) * 128];
    float s = 0.f;
    #pragma unroll
    for (int jj = 0; jj < 16; ++jj) {
      uint4 uu = rowp[jj];
      s += bf2f((unsigned short)(uu.x & 0xffffu)) * nhat[jj*8+0]
         + bf2f((unsigned short)(uu.x >> 16))     * nhat[jj*8+1]
         + bf2f((unsigned short)(uu.y & 0xffffu)) * nhat[jj*8+2]
         + bf2f((unsigned short)(uu.y >> 16))     * nhat[jj*8+3]
         + bf2f((unsigned short)(uu.z & 0xffffu)) * nhat[jj*8+4]
         + bf2f((unsigned short)(uu.z >> 16))     * nhat[jj*8+5]
         + bf2f((unsigned short)(uu.w & 0xffffu)) * nhat[jj*8+6]
         + bf2f((unsigned short)(uu.w >> 16))     * nhat[jj*8+7];
    }
    l_lds[l] = s + biasg[b * L_ + l];
  }
  __syncthreads();
  // ---- pass 5: final softmax -> out ----
  {
    float mx = -1e30f;
    for (int i = tid; i < 2048; i += 256) mx = fmaxf(mx, l_lds[i]);
    #pragma unroll
    for (int msk = 1; msk < 64; msk <<= 1) mx = fmaxf(mx, __shfl_xor(mx, msk));
    __syncthreads();
    if (lane == 0) red[wave] = mx;
    __syncthreads();
    mx = fmaxf(fmaxf(red[0], red[1]), fmaxf(red[2], red[3]));
    float sm = 0.f;
    for (int i = tid; i < 2048; i += 256) sm += __expf(l_lds[i] - mx);
    #pragma unroll
    for (int msk = 1; msk < 64; msk <<= 1) sm += __shfl_xor(sm, msk);
    __syncthreads();
    if (lane == 0) red[wave] = sm;
    __syncthreads();
    sm = red[0] + red[1] + red[2] + red[3];
    float inv = 1.f / sm;
    for (int i = tid; i < 2048; i += 256) out[b * L_ + i] = __expf(l_lds[i] - mx) * inv;
  }
}

// ---------------------------------------------------------------------------
extern "C" void kernel_launch(void* const* d_in, const int* in_sizes, int n_in,
                              void* d_out, int out_size, void* d_ws, size_t ws_size,
                              hipStream_t stream) {
  const int*   code = (const int*)d_in[0];
  const float* E    = (const float*)d_in[1];
  const float* bt   = (const float*)d_in[2];
  const float* Wx   = (const float*)d_in[3];
  const float* Wh   = (const float*)d_in[4];
  const float* bg   = (const float*)d_in[5];
  const float* c1w  = (const float*)d_in[6];
  const float* c1b  = (const float*)d_in[7];
  const float* c2w  = (const float*)d_in[8];
  const float* c2b  = (const float*)d_in[9];
  const float* c3w  = (const float*)d_in[10];
  const float* c3b  = (const float*)d_in[11];
  char* ws = (char*)d_ws;
  unsigned short* tokpad = (unsigned short*)(ws);               // 33,685,504 B
  unsigned short* l1pad  = (unsigned short*)(ws + 33685504);    // 16,842,752 B
  unsigned short* xproj  = (unsigned short*)(ws + 50528256);    // 50,331,648 B
  unsigned short* c2o    = (unsigned short*)(ws + 100859904);   // 16,777,216 B
  unsigned short* WxT    = (unsigned short*)(ws + 117637120);   //     49,152 B
  unsigned short* c1wT   = (unsigned short*)(ws + 117686272);   //    131,072 B
  unsigned short* c2wT   = (unsigned short*)(ws + 117817344);   //     65,536 B
  float*          htp    = (float*)(ws + 117882880);            //     16,384 B
  float*          biasg  = (float*)(ws + 117899264);            //    524,288 B
  // total ws use: 118,423,552 B

  k_prep <<<9232, 256, 0, stream>>>(code, E, bt, Wx, c1w, c2w, tokpad, l1pad, WxT, c1wT, c2wT, biasg);
  k_xproj<<<1024, 256, 0, stream>>>(tokpad, WxT, bg, xproj);
  k_scan <<<64, 192, 0, stream>>>(xproj, Wh, bg, htp);
  k_conv1<<<1024, 256, 0, stream>>>(tokpad, c1wT, c1b, l1pad);
  k_conv2<<<1024, 256, 0, stream>>>(l1pad, c2wT, c2b, c2o);
  k_final<<<64, 256, 0, stream>>>(tokpad, c2o, htp, c3w, c3b, biasg, (float*)d_out);
}

// Round 3
// 1697.465 us; speedup vs baseline: 1.3204x; 1.0413x over previous
//
#include <hip/hip_runtime.h>

#define B_ 64
#define L_ 2048
#define D_ 128
#define LP 2056   // padded rows per batch (3 left, 5 right incl. alignment)
#define PAD 3     // SAME-pad left for W=8

typedef __attribute__((ext_vector_type(8))) short short8;
typedef __attribute__((ext_vector_type(4))) float f32x4;

static __device__ __forceinline__ float bf2f(unsigned short u) {
  return __uint_as_float(((unsigned int)u) << 16);
}
static __device__ __forceinline__ unsigned short f2bf(float f) {
  unsigned int x = __float_as_uint(f);
  unsigned int r = (x + 0x7fffu + ((x >> 16) & 1u)) >> 16;  // RNE
  return (unsigned short)r;
}

// ---------------------------------------------------------------------------
// K0: gather tok -> bf16 padded [B,LP,128]; zero l1pad's pad rows; gather bias;
//     transpose weights to bf16 [n][k] layouts for MFMA B-fragments.
// ---------------------------------------------------------------------------
__global__ __launch_bounds__(256) void k_prep(
    const int* __restrict__ code, const float* __restrict__ E,
    const float* __restrict__ bias_table, const float* __restrict__ Wx,
    const float* __restrict__ c1w, const float* __restrict__ c2w,
    unsigned short* __restrict__ tokpad, unsigned short* __restrict__ l1pad,
    unsigned short* __restrict__ WxT, unsigned short* __restrict__ c1wT,
    unsigned short* __restrict__ c2wT, float* __restrict__ biasg)
{
  int id = blockIdx.x * 256 + threadIdx.x;
  const int N0 = B_ * LP * 16;            // tokpad in uint4 (8 bf16) chunks
  if (id < N0) {
    int b = id / (LP * 16); int rem = id % (LP * 16);
    int row = rem >> 4, c8 = rem & 15;
    uint4 o = {0u,0u,0u,0u};
    if (row >= PAD && row < PAD + L_) {
      int cd = code[b * L_ + (row - PAD)];
      const float4* e = (const float4*)(E + (size_t)cd * D_ + c8 * 8);
      float4 e0 = e[0], e1 = e[1];
      o.x = f2bf(e0.x) | ((unsigned int)f2bf(e0.y) << 16);
      o.y = f2bf(e0.z) | ((unsigned int)f2bf(e0.w) << 16);
      o.z = f2bf(e1.x) | ((unsigned int)f2bf(e1.y) << 16);
      o.w = f2bf(e1.z) | ((unsigned int)f2bf(e1.w) << 16);
    }
    ((uint4*)tokpad)[id] = o;
    return;
  }
  id -= N0;
  const int N1 = B_ * 8 * 8;              // l1pad pad rows (8 rows x 8 chunks)
  if (id < N1) {
    int b = id >> 6; int rem = id & 63; int ri = rem >> 3, c8 = rem & 7;
    int row = ri < 3 ? ri : (L_ + ri);    // 0,1,2, 2051..2055
    uint4 z = {0u,0u,0u,0u};
    ((uint4*)l1pad)[(b * LP + row) * 8 + c8] = z;
    return;
  }
  id -= N1;
  const int N2 = B_ * L_;
  if (id < N2) { biasg[id] = bias_table[code[id]]; return; }
  id -= N2;
  const int N3 = 192 * 128;               // WxT[c][d]
  if (id < N3) { int c = id >> 7, d = id & 127; WxT[id] = f2bf(Wx[d * 192 + c]); return; }
  id -= N3;
  const int N4 = 8 * 64 * 128;            // c1wT[w][c][d]
  if (id < N4) {
    int w = id >> 13, c = (id >> 7) & 63, d = id & 127;
    c1wT[id] = f2bf(c1w[(w * 128 + d) * 64 + c]); return;
  }
  id -= N4;
  const int N5 = 8 * 64 * 64;             // c2wT[w][c][d]
  if (id < N5) {
    int w = id >> 12, c = (id >> 6) & 63, d = id & 63;
    c2wT[id] = f2bf(c2w[(w * 64 + d) * 64 + c]);
  }
}

// ---------------------------------------------------------------------------
// K1: x_proj = tok @ Wx + b_gru[0]  -> bf16 [B,L,192]   (MFMA 16x16x32 bf16)
// ---------------------------------------------------------------------------
__global__ __launch_bounds__(256) void k_xproj(
    const unsigned short* __restrict__ tokpad, const unsigned short* __restrict__ WxT,
    const float* __restrict__ bg, unsigned short* __restrict__ xproj)
{
  __shared__ __align__(16) unsigned short At[128 * 136];
  __shared__ __align__(16) unsigned short Bt[192 * 136];
  int b = blockIdx.x >> 4;
  int l0 = (blockIdx.x & 15) << 7;
  int tid = threadIdx.x;
  for (int i = tid; i < 128 * 16; i += 256) {
    int row = i >> 4, c8 = i & 15;
    uint4 v = ((const uint4*)tokpad)[(b * LP + PAD + l0 + row) * 16 + c8];
    *((uint4*)&At[row * 136 + c8 * 8]) = v;
  }
  for (int i = tid; i < 192 * 16; i += 256) {
    int row = i >> 4, c8 = i & 15;
    uint4 v = ((const uint4*)WxT)[i];
    *((uint4*)&Bt[row * 136 + c8 * 8]) = v;
  }
  __syncthreads();
  int wave = tid >> 6, lane = tid & 63;
  int m = lane & 15, q = lane >> 4;
  f32x4 acc[2][12];
  #pragma unroll
  for (int mt = 0; mt < 2; ++mt)
    #pragma unroll
    for (int nt = 0; nt < 12; ++nt) acc[mt][nt] = (f32x4){0.f,0.f,0.f,0.f};
  #pragma unroll
  for (int ks = 0; ks < 4; ++ks) {
    int kof = ks * 32 + q * 8;
    short8 a[2], bb[12];
    #pragma unroll
    for (int mt = 0; mt < 2; ++mt)
      a[mt] = *(const short8*)&At[(wave * 32 + mt * 16 + m) * 136 + kof];
    #pragma unroll
    for (int nt = 0; nt < 12; ++nt)
      bb[nt] = *(const short8*)&Bt[(nt * 16 + m) * 136 + kof];
    #pragma unroll
    for (int mt = 0; mt < 2; ++mt)
      #pragma unroll
      for (int nt = 0; nt < 12; ++nt)
        acc[mt][nt] = __builtin_amdgcn_mfma_f32_16x16x32_bf16(a[mt], bb[nt], acc[mt][nt], 0, 0, 0);
  }
  #pragma unroll
  for (int mt = 0; mt < 2; ++mt) {
    int lrow = l0 + wave * 32 + mt * 16 + q * 4;
    #pragma unroll
    for (int nt = 0; nt < 12; ++nt) {
      int c = nt * 16 + m;                 // C col = lane&15
      float b0 = bg[c];
      #pragma unroll
      for (int r = 0; r < 4; ++r)
        xproj[(size_t)(b * L_ + lrow + r) * 192 + c] = f2bf(acc[mt][nt][r] + b0);
    }
  }
}

// ---------------------------------------------------------------------------
// K2: conv1 = relu(conv8(tok,c1w)+c1b) -> bf16 l1pad rows [3,2051)
// ---------------------------------------------------------------------------
__global__ __launch_bounds__(256) void k_conv1(
    const unsigned short* __restrict__ tokpad, const unsigned short* __restrict__ c1wT,
    const float* __restrict__ c1b, unsigned short* __restrict__ l1pad)
{
  __shared__ __align__(16) unsigned short At[135 * 136];
  __shared__ __align__(16) unsigned short Bw[64 * 136];
  int b = blockIdx.x >> 4;
  int l0 = (blockIdx.x & 15) << 7;
  int tid = threadIdx.x;
  for (int i = tid; i < 135 * 16; i += 256) {
    int row = i >> 4, c8 = i & 15;
    uint4 v = ((const uint4*)tokpad)[(b * LP + l0 + row) * 16 + c8];
    *((uint4*)&At[row * 136 + c8 * 8]) = v;
  }
  int wave = tid >> 6, lane = tid & 63;
  int m = lane & 15, q = lane >> 4;
  f32x4 acc[2][4];
  #pragma unroll
  for (int mt = 0; mt < 2; ++mt)
    #pragma unroll
    for (int nt = 0; nt < 4; ++nt) acc[mt][nt] = (f32x4){0.f,0.f,0.f,0.f};
  for (int w = 0; w < 8; ++w) {
    __syncthreads();                       // covers At (w=0) and Bw reuse
    for (int i = tid; i < 64 * 16; i += 256) {
      int row = i >> 4, c8 = i & 15;
      uint4 v = ((const uint4*)c1wT)[(w * 64 + row) * 16 + c8];
      *((uint4*)&Bw[row * 136 + c8 * 8]) = v;
    }
    __syncthreads();
    #pragma unroll
    for (int ks = 0; ks < 4; ++ks) {
      int kof = ks * 32 + q * 8;
      short8 a[2], bb[4];
      #pragma unroll
      for (int mt = 0; mt < 2; ++mt)
        a[mt] = *(const short8*)&At[(wave * 32 + mt * 16 + m + w) * 136 + kof];
      #pragma unroll
      for (int nt = 0; nt < 4; ++nt)
        bb[nt] = *(const short8*)&Bw[(nt * 16 + m) * 136 + kof];
      #pragma unroll
      for (int mt = 0; mt < 2; ++mt)
        #pragma unroll
        for (int nt = 0; nt < 4; ++nt)
          acc[mt][nt] = __builtin_amdgcn_mfma_f32_16x16x32_bf16(a[mt], bb[nt], acc[mt][nt], 0, 0, 0);
    }
  }
  #pragma unroll
  for (int mt = 0; mt < 2; ++mt) {
    int lrow = l0 + wave * 32 + mt * 16 + q * 4;
    #pragma unroll
    for (int nt = 0; nt < 4; ++nt) {
      int c = nt * 16 + m;
      float bias = c1b[c];
      #pragma unroll
      for (int r = 0; r < 4; ++r) {
        float v = fmaxf(acc[mt][nt][r] + bias, 0.f);
        l1pad[(size_t)(b * LP + PAD + lrow + r) * 64 + c] = f2bf(v);
      }
    }
  }
}

// ---------------------------------------------------------------------------
// K3: conv2 (+c2b, pre h_t multiply) -> bf16 c2out [B,L,64]
// ---------------------------------------------------------------------------
__global__ __launch_bounds__(256) void k_conv2(
    const unsigned short* __restrict__ l1pad, const unsigned short* __restrict__ c2wT,
    const float* __restrict__ c2b, unsigned short* __restrict__ c2o)
{
  __shared__ __align__(16) unsigned short At[135 * 72];
  __shared__ __align__(16) unsigned short Bw[64 * 72];
  int b = blockIdx.x >> 4;
  int l0 = (blockIdx.x & 15) << 7;
  int tid = threadIdx.x;
  for (int i = tid; i < 135 * 8; i += 256) {
    int row = i >> 3, c8 = i & 7;
    uint4 v = ((const uint4*)l1pad)[(b * LP + l0 + row) * 8 + c8];
    *((uint4*)&At[row * 72 + c8 * 8]) = v;
  }
  int wave = tid >> 6, lane = tid & 63;
  int m = lane & 15, q = lane >> 4;
  f32x4 acc[2][4];
  #pragma unroll
  for (int mt = 0; mt < 2; ++mt)
    #pragma unroll
    for (int nt = 0; nt < 4; ++nt) acc[mt][nt] = (f32x4){0.f,0.f,0.f,0.f};
  for (int w = 0; w < 8; ++w) {
    __syncthreads();
    for (int i = tid; i < 64 * 8; i += 256) {
      int row = i >> 3, c8 = i & 7;
      uint4 v = ((const uint4*)c2wT)[(w * 64 + row) * 8 + c8];
      *((uint4*)&Bw[row * 72 + c8 * 8]) = v;
    }
    __syncthreads();
    #pragma unroll
    for (int ks = 0; ks < 2; ++ks) {
      int kof = ks * 32 + q * 8;
      short8 a[2], bb[4];
      #pragma unroll
      for (int mt = 0; mt < 2; ++mt)
        a[mt] = *(const short8*)&At[(wave * 32 + mt * 16 + m + w) * 72 + kof];
      #pragma unroll
      for (int nt = 0; nt < 4; ++nt)
        bb[nt] = *(const short8*)&Bw[(nt * 16 + m) * 72 + kof];
      #pragma unroll
      for (int mt = 0; mt < 2; ++mt)
        #pragma unroll
        for (int nt = 0; nt < 4; ++nt)
          acc[mt][nt] = __builtin_amdgcn_mfma_f32_16x16x32_bf16(a[mt], bb[nt], acc[mt][nt], 0, 0, 0);
    }
  }
  #pragma unroll
  for (int mt = 0; mt < 2; ++mt) {
    int lrow = l0 + wave * 32 + mt * 16 + q * 4;
    #pragma unroll
    for (int nt = 0; nt < 4; ++nt) {
      int c = nt * 16 + m;
      float bias = c2b[c];
      #pragma unroll
      for (int r = 0; r < 4; ++r)
        c2o[(size_t)(b * L_ + lrow + r) * 64 + c] = f2bf(acc[mt][nt][r] + bias);
    }
  }
}

// ---------------------------------------------------------------------------
// K4 v3: GRU scan. 3 waves per batch (one per gate). Lane o = wave*64+j owns
// output column o. Weights in 16 EXPLICIT float4 registers (named scalars —
// promote-alloca cannot bail; R1's float w[64] stayed in scratch, VGPR=44).
// Waves 0/1 apply sigmoid pre-barrier; wave2 only does tanh+blend post-barrier.
// ---------------------------------------------------------------------------
__global__ __launch_bounds__(192, 1) void k_scan(
    const unsigned short* __restrict__ xproj, const float* __restrict__ Wh,
    const float* __restrict__ bg, float* __restrict__ h_t)
{
  int b = blockIdx.x;
  int tid = threadIdx.x;
  int wave = tid >> 6, j = tid & 63;
  int o = wave * 64 + j;                  // output column 0..191

#define DECL_W(i) float4 w##i = {Wh[(4*i+0)*192+o], Wh[(4*i+1)*192+o], \
                                 Wh[(4*i+2)*192+o], Wh[(4*i+3)*192+o]};
  DECL_W(0)  DECL_W(1)  DECL_W(2)  DECL_W(3)
  DECL_W(4)  DECL_W(5)  DECL_W(6)  DECL_W(7)
  DECL_W(8)  DECL_W(9)  DECL_W(10) DECL_W(11)
  DECL_W(12) DECL_W(13) DECL_W(14) DECL_W(15)
#undef DECL_W
  float bias = bg[192 + o];               // b_gru[1][o]

  __shared__ __align__(16) float h_lds[64];
  __shared__ float s_z[64];
  __shared__ float s_r[64];
  if (wave == 2) h_lds[j] = 0.f;
  float h_old = 0.f;                      // wave2's private copy of h[j]

  const unsigned short* xp = xproj + (size_t)b * L_ * 192 + o;
  unsigned short x0 = xp[0];
  unsigned short x1 = xp[192];
  const float4* hl4 = (const float4*)h_lds;

  for (int t = 0; t < L_; ++t) {
    __syncthreads();                      // barrier A: h_lds ready, s_* free
    int tn = (t + 2 < L_) ? t + 2 : (L_ - 1);
    unsigned short x2 = xp[(size_t)tn * 192];

    float a0 = bias, a1 = 0.f, a2 = 0.f, a3 = 0.f;
#define ACC_W(i) { float4 h4 = hl4[i]; \
    a0 = fmaf(h4.x, w##i.x, a0); a1 = fmaf(h4.y, w##i.y, a1); \
    a2 = fmaf(h4.z, w##i.z, a2); a3 = fmaf(h4.w, w##i.w, a3); }
    ACC_W(0)  ACC_W(1)  ACC_W(2)  ACC_W(3)
    ACC_W(4)  ACC_W(5)  ACC_W(6)  ACC_W(7)
    ACC_W(8)  ACC_W(9)  ACC_W(10) ACC_W(11)
    ACC_W(12) ACC_W(13) ACC_W(14) ACC_W(15)
#undef ACC_W
    float s = (a0 + a1) + (a2 + a3);      // recurrent preact for column o
    float xv = bf2f(x0);

    if (wave == 0)      s_z[j] = 1.f / (1.f + __expf(-(xv + s)));   // z
    else if (wave == 1) s_r[j] = 1.f / (1.f + __expf(-(xv + s)));   // r
    __syncthreads();                      // barrier B: gates visible, h_lds free
    if (wave == 2) {
      float z = s_z[j], r = s_r[j];
      float e2 = __expf(-2.f * (xv + r * s));
      float hh = (1.f - e2) / (1.f + e2); // tanh
      h_old = z * h_old + (1.f - z) * hh;
      h_lds[j] = h_old;
    }
    x0 = x1; x1 = x2;
  }
  if (wave == 2) h_t[b * 64 + j] = h_old;
}

// ---------------------------------------------------------------------------
// K5: per-batch tail: L2=c2o*h_t -> l2norm -> conv3 -> softmax alpha ->
//     n_hat = sum alpha*tok -> logits = tok.n_hat + bias -> softmax -> out
// ---------------------------------------------------------------------------
__global__ __launch_bounds__(256) void k_final(
    const unsigned short* __restrict__ tokpad, const unsigned short* __restrict__ c2o,
    const float* __restrict__ h_t, const float* __restrict__ c3w,
    const float* __restrict__ c3b, const float* __restrict__ biasg,
    float* __restrict__ out)
{
  __shared__ float Lf[71 * 65];
  __shared__ float a_lds[2048];
  __shared__ float l_lds[2048];
  __shared__ float red[256];
  __shared__ float nred[512];
  __shared__ float nhat[128];
  __shared__ float ht[64];
  __shared__ float c3[512];
  int b = blockIdx.x, tid = threadIdx.x, lane = tid & 63, wave = tid >> 6;
  if (tid < 64) ht[tid] = h_t[b * 64 + tid];
  for (int i = tid; i < 512; i += 256) c3[i] = c3w[i];
  float c3bias = c3b[0];
  __syncthreads();
  // ---- pass 1: a_logits via normalized features + conv3 (tiles of 64 l) ----
  for (int tile = 0; tile < 32; ++tile) {
    int lt = tile << 6;
    for (int i0 = wave; i0 < 71; i0 += 4) {
      int l = lt - 3 + i0;
      float v = 0.f;
      if (l >= 0 && l < L_) v = bf2f(c2o[((size_t)b * L_ + l) * 64 + lane]) * ht[lane];
      float ss = v * v;
      #pragma unroll
      for (int msk = 1; msk < 64; msk <<= 1) ss += __shfl_xor(ss, msk);
      Lf[i0 * 65 + lane] = v * rsqrtf(ss + 1e-12f);
    }
    __syncthreads();
    {
      int u = lane, part = wave;
      float p = 0.f;
      #pragma unroll
      for (int w = 0; w < 8; ++w)
        #pragma unroll
        for (int cc = 0; cc < 16; ++cc) {
          int c = part * 16 + cc;
          p += Lf[(u + w) * 65 + c] * c3[w * 64 + c];
        }
      red[tid] = p;
    }
    __syncthreads();
    if (tid < 64) a_lds[lt + tid] = red[tid] + red[64 + tid] + red[128 + tid] + red[192 + tid] + c3bias;
    __syncthreads();
  }
  // ---- pass 2: softmax alpha over 2048 ----
  {
    float mx = -1e30f;
    for (int i = tid; i < 2048; i += 256) mx = fmaxf(mx, a_lds[i]);
    #pragma unroll
    for (int msk = 1; msk < 64; msk <<= 1) mx = fmaxf(mx, __shfl_xor(mx, msk));
    if (lane == 0) red[wave] = mx;
    __syncthreads();
    mx = fmaxf(fmaxf(red[0], red[1]), fmaxf(red[2], red[3]));
    float sm = 0.f;
    for (int i = tid; i < 2048; i += 256) sm += __expf(a_lds[i] - mx);
    #pragma unroll
    for (int msk = 1; msk < 64; msk <<= 1) sm += __shfl_xor(sm, msk);
    __syncthreads();
    if (lane == 0) red[wave] = sm;
    __syncthreads();
    sm = red[0] + red[1] + red[2] + red[3];
    float inv = 1.f / sm;
    for (int i = tid; i < 2048; i += 256) a_lds[i] = __expf(a_lds[i] - mx) * inv;
    __syncthreads();
  }
  // ---- pass 3: n_hat[128] = sum_l alpha_l * tok[l][:] ----
  {
    int d2 = tid & 63, g = tid >> 6;
    float ax = 0.f, ay = 0.f;
    for (int l = g; l < L_; l += 4) {
      unsigned int uu = *(const unsigned int*)&tokpad[((size_t)b * LP + PAD + l) * 128 + d2 * 2];
      float al = a_lds[l];
      ax += al * bf2f((unsigned short)(uu & 0xffffu));
      ay += al * bf2f((unsigned short)(uu >> 16));
    }
    nred[g * 128 + d2 * 2] = ax;
    nred[g * 128 + d2 * 2 + 1] = ay;
    __syncthreads();
    if (tid < 128) nhat[tid] = nred[tid] + nred[128 + tid] + nred[256 + tid] + nred[384 + tid];
    __syncthreads();
  }
  // ---- pass 4: logits = tok . n_hat + bias ----
  for (int li = 0; li < 8; ++li) {
    int l = li * 256 + tid;
    const uint4* rowp = (const uint4*)&tokpad[((size_t)b * LP + PAD + l) * 128];
    float s = 0.f;
    #pragma unroll
    for (int jj = 0; jj < 16; ++jj) {
      uint4 uu = rowp[jj];
      s += bf2f((unsigned short)(uu.x & 0xffffu)) * nhat[jj*8+0]
         + bf2f((unsigned short)(uu.x >> 16))     * nhat[jj*8+1]
         + bf2f((unsigned short)(uu.y & 0xffffu)) * nhat[jj*8+2]
         + bf2f((unsigned short)(uu.y >> 16))     * nhat[jj*8+3]
         + bf2f((unsigned short)(uu.z & 0xffffu)) * nhat[jj*8+4]
         + bf2f((unsigned short)(uu.z >> 16))     * nhat[jj*8+5]
         + bf2f((unsigned short)(uu.w & 0xffffu)) * nhat[jj*8+6]
         + bf2f((unsigned short)(uu.w >> 16))     * nhat[jj*8+7];
    }
    l_lds[l] = s + biasg[b * L_ + l];
  }
  __syncthreads();
  // ---- pass 5: final softmax -> out ----
  {
    float mx = -1e30f;
    for (int i = tid; i < 2048; i += 256) mx = fmaxf(mx, l_lds[i]);
    #pragma unroll
    for (int msk = 1; msk < 64; msk <<= 1) mx = fmaxf(mx, __shfl_xor(mx, msk));
    __syncthreads();
    if (lane == 0) red[wave] = mx;
    __syncthreads();
    mx = fmaxf(fmaxf(red[0], red[1]), fmaxf(red[2], red[3]));
    float sm = 0.f;
    for (int i = tid; i < 2048; i += 256) sm += __expf(l_lds[i] - mx);
    #pragma unroll
    for (int msk = 1; msk < 64; msk <<= 1) sm += __shfl_xor(sm, msk);
    __syncthreads();
    if (lane == 0) red[wave] = sm;
    __syncthreads();
    sm = red[0] + red[1] + red[2] + red[3];
    float inv = 1.f / sm;
    for (int i = tid; i < 2048; i += 256) out[b * L_ + i] = __expf(l_lds[i] - mx) * inv;
  }
}

// ---------------------------------------------------------------------------
extern "C" void kernel_launch(void* const* d_in, const int* in_sizes, int n_in,
                              void* d_out, int out_size, void* d_ws, size_t ws_size,
                              hipStream_t stream) {
  const int*   code = (const int*)d_in[0];
  const float* E    = (const float*)d_in[1];
  const float* bt   = (const float*)d_in[2];
  const float* Wx   = (const float*)d_in[3];
  const float* Wh   = (const float*)d_in[4];
  const float* bg   = (const float*)d_in[5];
  const float* c1w  = (const float*)d_in[6];
  const float* c1b  = (const float*)d_in[7];
  const float* c2w  = (const float*)d_in[8];
  const float* c2b  = (const float*)d_in[9];
  const float* c3w  = (const float*)d_in[10];
  const float* c3b  = (const float*)d_in[11];
  char* ws = (char*)d_ws;
  unsigned short* tokpad = (unsigned short*)(ws);               // 33,685,504 B
  unsigned short* l1pad  = (unsigned short*)(ws + 33685504);    // 16,842,752 B
  unsigned short* xproj  = (unsigned short*)(ws + 50528256);    // 50,331,648 B
  unsigned short* c2o    = (unsigned short*)(ws + 100859904);   // 16,777,216 B
  unsigned short* WxT    = (unsigned short*)(ws + 117637120);   //     49,152 B
  unsigned short* c1wT   = (unsigned short*)(ws + 117686272);   //    131,072 B
  unsigned short* c2wT   = (unsigned short*)(ws + 117817344);   //     65,536 B
  float*          htp    = (float*)(ws + 117882880);            //     16,384 B
  float*          biasg  = (float*)(ws + 117899264);            //    524,288 B
  // total ws use: 118,423,552 B

  k_prep <<<9232, 256, 0, stream>>>(code, E, bt, Wx, c1w, c2w, tokpad, l1pad, WxT, c1wT, c2wT, biasg);
  k_xproj<<<1024, 256, 0, stream>>>(tokpad, WxT, bg, xproj);
  k_scan <<<64, 192, 0, stream>>>(xproj, Wh, bg, htp);
  k_conv1<<<1024, 256, 0, stream>>>(tokpad, c1wT, c1b, l1pad);
  k_conv2<<<1024, 256, 0, stream>>>(l1pad, c2wT, c2b, c2o);
  k_final<<<64, 256, 0, stream>>>(tokpad, c2o, htp, c3w, c3b, biasg, (float*)d_out);
}